// Round 8
// baseline (2410.355 us; speedup 1.0000x reference)
//
#include <hip/hip_runtime.h>
#include <cstdint>
#include <cstddef>

// ---------------------------------------------------------------------------
// PointNet++ SA module (multi-scale grouping) with attention gate.
// B=16, N=4096, C_IN=64, NPOINT=1024, radii (0.2,0.4), nsamples (32,64),
// MLPs ((64,64,128),(64,64,128)), C_TOTAL=256. Inputs f32, output f32.
// Round 8: launch fusion 6->3 (fps+wt-transpose / ballq+att / mlp32+mlp64)
// and FPS dependency-depth cuts (parallel half-scans, tree coord select).
// Selection semantics (non-contracted f32, (value,-index) order) unchanged.
// ---------------------------------------------------------------------------

constexpr int B_ = 16, N_ = 4096, S_ = 1024;
constexpr int WT_G = 67*64 + 64*64 + 128*64 + 64 + 64 + 128; // 16832 floats/group

// workspace layout in 4-byte units
constexpr int WS_XYZF = 0;                       // float4[B*N]
constexpr int WS_NXYZ = B_*N_*4;                 // float[B*S*3]
constexpr int WS_ATT  = WS_NXYZ + B_*S_*3;       // float[B*256]
constexpr int WS_WT   = WS_ATT + B_*256;         // float[2*WT_G]
constexpr int WS_IDX0 = WS_WT + 2*WT_G;          // int[B*S*32]
constexpr int WS_IDX1 = WS_IDX0 + B_*S_*32;      // int[B*S*64]

// ---------------------------------------------------------------------------
// K1: FPS (blocks 0..15, one per batch) + weight transpose (blocks 16..147).
// FPS: 256 thr (4 waves, 1/SIMD) x 16 pts/thread. Per iteration: no-FMA f32
// distance+min update (bit-exact vs np), tree max + two parallel half-scans
// (smallest p), DPP uint wave max, ballot+ctz+readlane smallest index,
// winner tree-selects coords by psel bits and forwards (val,~idx) key +
// coords to double-buffered LDS, ONE barrier, all threads combine 4
// candidates (u64 max tree, lexicographic => np-exact).
// Epilogue: new_xyz (ws + out) and xyzf (float4-padded) written coalesced.
// ---------------------------------------------------------------------------
__global__ __launch_bounds__(256) void fps_wt_kernel(
    const float* __restrict__ xyz,
    const float* __restrict__ w00, const float* __restrict__ w01,
    const float* __restrict__ w02, const float* __restrict__ b00,
    const float* __restrict__ b01, const float* __restrict__ b02,
    const float* __restrict__ w10, const float* __restrict__ w11,
    const float* __restrict__ w12, const float* __restrict__ b10,
    const float* __restrict__ b11, const float* __restrict__ b12,
    float4* __restrict__ xyzf, float* __restrict__ wt,
    float* __restrict__ nxyz, float* __restrict__ out_nxyz) {
  constexpr int PPT = 16;
  __shared__ float sx[N_*3];
  __shared__ int   selidx[S_];
  __shared__ alignas(16) unsigned long long redP[2][4];
  __shared__ alignas(16) float4 redC[2][4];

  if (blockIdx.x >= B_) {
    // ---- weight-transpose role (runs on idle CUs during FPS) ----
    int wid = (blockIdx.x - B_) * 256 + threadIdx.x;
    if (wid >= 2*WT_G) return;
    int g = wid / WT_G, r = wid % WT_G;
    float val;
    if (r < 4288) {                    // layer0: w (64,67) -> wt0[c*64+o]
      int c = r >> 6, o = r & 63;
      val = (g ? w10 : w00)[o*67 + c];
    } else if (r < 8384) {             // layer1: w (64,64) -> wt1[c*64+o]
      int rr = r - 4288; int c = rr >> 6, o = rr & 63;
      val = (g ? w11 : w01)[o*64 + c];
    } else if (r < 16576) {            // layer2: w (128,64) -> wt2[c*128+o]
      int rr = r - 8384; int c = rr >> 7, o = rr & 127;
      val = (g ? w12 : w02)[o*64 + c];
    } else {                           // biases
      int rr = r - 16576;
      val = (rr < 64)  ? (g ? b10 : b00)[rr]
          : (rr < 128) ? (g ? b11 : b01)[rr - 64]
                       : (g ? b12 : b02)[rr - 128];
    }
    wt[g*WT_G + r] = val;
    return;
  }

  // ---- FPS role ----
  const int b = blockIdx.x, t = threadIdx.x;
  const int wv = t >> 6;  // wave id 0..3
  const float* xr = xyz + (size_t)b * N_ * 3;
  for (int k = t; k < N_*3; k += 256) sx[k] = xr[k];   // coalesced stage
  if (t == 0) selidx[0] = 0;   // first sampled index is 0 (matches reference)
  __syncthreads();
  float px[PPT], py[PPT], pz[PPT], m[PPT];
#pragma unroll
  for (int p = 0; p < PPT; ++p) {
    int idx = t * PPT + p;
    px[p] = sx[idx*3+0]; py[p] = sx[idx*3+1]; pz[p] = sx[idx*3+2];
    m[p] = 1e10f;
  }
  float lx = sx[0], ly = sx[1], lz = sx[2];
  for (int i = 1; i < S_; ++i) {
    // ---- distance + running-min update (bit-exact np arithmetic) ----
#pragma unroll
    for (int p = 0; p < PPT; ++p) {
      float dx = __fsub_rn(px[p], lx), dy = __fsub_rn(py[p], ly), dz = __fsub_rn(pz[p], lz);
      float d = __fadd_rn(__fadd_rn(__fmul_rn(dx,dx), __fmul_rn(dy,dy)), __fmul_rn(dz,dz));
      m[p] = fminf(m[p], d);
    }
    // ---- local argmax: max tree + two parallel half-scans ----
    float h0 = fmaxf(fmaxf(m[0],  m[1]),  fmaxf(m[2],  m[3]));
    float h1 = fmaxf(fmaxf(m[4],  m[5]),  fmaxf(m[6],  m[7]));
    float h2 = fmaxf(fmaxf(m[8],  m[9]),  fmaxf(m[10], m[11]));
    float h3 = fmaxf(fmaxf(m[12], m[13]), fmaxf(m[14], m[15]));
    float lo = fmaxf(h0, h1), hi = fmaxf(h2, h3);
    float bv = fmaxf(lo, hi);
    int blo = 7, bhi = 15;
#pragma unroll
    for (int p = 6; p >= 0; --p)  if (m[p] == bv) blo = p;   // smallest in [0,8)
#pragma unroll
    for (int p = 14; p >= 8; --p) if (m[p] == bv) bhi = p;   // smallest in [8,16)
    const int bp = (lo == bv) ? blo : bhi;
    const int bi = t * PPT + bp;
    // ---- wave max via DPP (uint compare valid: all m >= 0, no NaN) ----
    unsigned vm = __float_as_uint(bv);
#define DPP_MAX(ctrl) { unsigned o = (unsigned)__builtin_amdgcn_update_dpp((int)vm, (int)vm, (ctrl), 0xf, 0xf, false); vm = vm > o ? vm : o; }
    DPP_MAX(0x111)  // row_shr:1
    DPP_MAX(0x112)  // row_shr:2
    DPP_MAX(0x114)  // row_shr:4
    DPP_MAX(0x118)  // row_shr:8
    DPP_MAX(0x142)  // row_bcast:15
    DPP_MAX(0x143)  // row_bcast:31
#undef DPP_MAX
    const unsigned wmaxu = (unsigned)__builtin_amdgcn_readlane((int)vm, 63);
    // smallest index attaining the wave max: lanes are index-ordered
    const unsigned long long mk = __ballot(__float_as_uint(bv) == wmaxu);
    const int fl = (int)__builtin_ctzll(mk);
    const int widx = __builtin_amdgcn_readlane(bi, fl);
    const int par = i & 1;
    // ---- winner lane forwards packed key + its point's coords (tree sel) ----
    if (t == (widx >> 4)) {
      const int ps = widx & 15;
      float tx[8], ty[8], tz[8];
#pragma unroll
      for (int q = 0; q < 8; ++q) {      // level 1: bit0
        bool s = ps & 1;
        tx[q] = s ? px[2*q+1] : px[2*q];
        ty[q] = s ? py[2*q+1] : py[2*q];
        tz[q] = s ? pz[2*q+1] : pz[2*q];
      }
#pragma unroll
      for (int q = 0; q < 4; ++q) {      // level 2: bit1
        bool s = ps & 2;
        tx[q] = s ? tx[2*q+1] : tx[2*q];
        ty[q] = s ? ty[2*q+1] : ty[2*q];
        tz[q] = s ? tz[2*q+1] : tz[2*q];
      }
#pragma unroll
      for (int q = 0; q < 2; ++q) {      // level 3: bit2
        bool s = ps & 4;
        tx[q] = s ? tx[2*q+1] : tx[2*q];
        ty[q] = s ? ty[2*q+1] : ty[2*q];
        tz[q] = s ? tz[2*q+1] : tz[2*q];
      }
      bool s = ps & 8;                   // level 4: bit3
      float gx = s ? tx[1] : tx[0];
      float gy = s ? ty[1] : ty[0];
      float gz = s ? tz[1] : tz[0];
      redP[par][wv] = ((unsigned long long)wmaxu << 32) | (unsigned)(~widx);
      redC[par][wv] = make_float4(gx, gy, gz, 0.f);
    }
    __syncthreads();
    // ---- all threads: combine 4 wave candidates (broadcast LDS reads) ----
    ulonglong2 pA = *(const ulonglong2*)&redP[par][0];
    ulonglong2 pB = *(const ulonglong2*)&redP[par][2];
    float4 c0 = redC[par][0], c1 = redC[par][1];
    float4 c2 = redC[par][2], c3 = redC[par][3];
    unsigned long long q0 = pA.x > pA.y ? pA.x : pA.y;
    unsigned long long q1 = pB.x > pB.y ? pB.x : pB.y;
    unsigned long long win = q0 > q1 ? q0 : q1;
    const int fi = (int)(~(unsigned)win);   // global index of selected point
    const int ws = fi >> 10;                // winning wave (1024 idx per wave)
    float4 s0 = (ws & 1) ? c1 : c0;
    float4 s1 = (ws & 1) ? c3 : c2;
    float4 fc = (ws & 2) ? s1 : s0;
    lx = fc.x; ly = fc.y; lz = fc.z;
    if (t == 0) selidx[i] = fi;
  }
  __syncthreads();
  // epilogue: coalesced write of new_xyz (ws + out) and xyzf (float4-padded)
  for (int k = t; k < S_; k += 256) {
    int id = selidx[k];
    float x = sx[id*3], y = sx[id*3+1], z = sx[id*3+2];
    int o = (b * S_ + k) * 3;
    nxyz[o] = x; nxyz[o+1] = y; nxyz[o+2] = z;
    out_nxyz[o] = x; out_nxyz[o+1] = y; out_nxyz[o+2] = z;
  }
  for (int k = t; k < N_; k += 256) {
    float4 v; v.x = sx[k*3]; v.y = sx[k*3+1]; v.z = sx[k*3+2]; v.w = 0.f;
    xyzf[b * N_ + k] = v;
  }
}

// ---------------------------------------------------------------------------
// K2: fused dual-radius ball query (blocks 0..4095) + attention gate
// (blocks 4096..4111). Ball query: bit-exact d2 < r2 in non-contracted f32;
// first-NS in ascending index order; pad with first hit.
// ---------------------------------------------------------------------------
__global__ __launch_bounds__(256) void ballq_att_kernel(
    const float4* __restrict__ xyzf, const float* __restrict__ nxyz,
    int* __restrict__ idx0buf, int* __restrict__ idx1buf,
    const float* __restrict__ w_att, const float* __restrict__ b_att,
    float* __restrict__ att) {
  __shared__ float ai[3 * S_];
  if (blockIdx.x >= B_*S_/4) {
    // ---- attention role ----
    int b = blockIdx.x - B_*S_/4, t = threadIdx.x;
    for (int k = t; k < 3 * S_; k += 256) {
      int d = k >> 10, s = k & 1023;
      ai[k] = nxyz[(b * S_ + s) * 3 + d];
    }
    __syncthreads();
    float acc = b_att[t];
#pragma unroll 8
    for (int k = 0; k < 3 * S_; ++k)
      acc = fmaf(ai[k], w_att[k * 256 + t], acc);
    att[b * 256 + t] = 1.f / (1.f + expf(-acc));
    return;
  }
  // ---- ball-query role ----
  const float r2a = (float)(0.2 * 0.2), r2b = (float)(0.4 * 0.4);
  int lane = threadIdx.x & 63;
  int cid = blockIdx.x * 4 + (threadIdx.x >> 6);
  int b = cid >> 10;
  float cx = nxyz[cid*3], cy = nxyz[cid*3+1], cz = nxyz[cid*3+2];
  const float4* xb = xyzf + b * N_;
  int cnt0 = 0, cnt1 = 0, first0 = 0, first1 = 0;
  const unsigned long long below = (1ull << lane) - 1ull;
  for (int base = 0; base < N_; base += 64) {
    float4 P = xb[base + lane];
    float dx = __fsub_rn(cx, P.x), dy = __fsub_rn(cy, P.y), dz = __fsub_rn(cz, P.z);
    float d2 = __fadd_rn(__fadd_rn(__fmul_rn(dx,dx), __fmul_rn(dy,dy)), __fmul_rn(dz,dz));
    bool h0 = d2 < r2a, h1 = d2 < r2b;
    unsigned long long m0 = __ballot(h0), m1 = __ballot(h1);
    if (cnt0 == 0 && m0 != 0ull) first0 = base + (int)__builtin_ctzll(m0);
    if (cnt1 == 0 && m1 != 0ull) first1 = base + (int)__builtin_ctzll(m1);
    if (h0) {
      int pos = cnt0 + (int)__popcll(m0 & below);
      if (pos < 32) idx0buf[cid * 32 + pos] = base + lane;
    }
    if (h1) {
      int pos = cnt1 + (int)__popcll(m1 & below);
      if (pos < 64) idx1buf[cid * 64 + pos] = base + lane;
    }
    cnt0 += (int)__popcll(m0);
    cnt1 += (int)__popcll(m1);
    if (cnt0 >= 32 && cnt1 >= 64) break;
  }
  if (cnt0 < 32)
    for (int p = cnt0 + lane; p < 32; p += 64) idx0buf[cid * 32 + p] = first0;
  if (cnt1 < 64)
    for (int p = cnt1 + lane; p < 64; p += 64) idx1buf[cid * 64 + p] = first1;
}

// ---------------------------------------------------------------------------
// K3: GEMM-tiled fused group + MLP + maxpool + attention + store.
// 256 threads (4 waves), 128 columns/block. og = t&15, cg = t>>4.
// Both groups dispatched from one kernel (uniform per-block branch).
// ---------------------------------------------------------------------------
template<int NS>
__device__ __forceinline__ void mlp_body(int bi, float* xs,
    const float4* __restrict__ xyzf, const float* __restrict__ feats,
    const float* __restrict__ nxyz, const float* __restrict__ att,
    const int* __restrict__ idxbuf, const float* __restrict__ wt,
    float* __restrict__ outf, int g) {
  constexpr int NCEN = 128 / NS;
  constexpr int XS = 132;
  float* red = xs;
  const int t = threadIdx.x;
  const int cid0 = bi * NCEN;
  const int b = cid0 >> 10;

  {
    const int col = t & 127, h = t >> 7;
    const int cidg = cid0 + col / NS;
    const int j = col % NS;
    const int p = idxbuf[cidg * NS + j];
    if (h == 0) {
      float4 P = xyzf[b * N_ + p];
      xs[0*XS+col] = __fsub_rn(P.x, nxyz[cidg*3+0]);
      xs[1*XS+col] = __fsub_rn(P.y, nxyz[cidg*3+1]);
      xs[2*XS+col] = __fsub_rn(P.z, nxyz[cidg*3+2]);
    }
    const float4* f4 = (const float4*)(feats + (size_t)(b*N_+p)*64) + h*8;
#pragma unroll
    for (int q = 0; q < 8; ++q) {
      float4 u = f4[q];
      int r = 3 + h*32 + q*4;
      xs[(r+0)*XS+col]=u.x; xs[(r+1)*XS+col]=u.y; xs[(r+2)*XS+col]=u.z; xs[(r+3)*XS+col]=u.w;
    }
  }
  __syncthreads();

  const int og = t & 15, cg = t >> 4;
  const float* w0  = wt;
  const float* w1  = wt + 67*64;
  const float* w2  = w1 + 64*64;
  const float* bb0 = w2 + 64*128;
  const float* bb1 = bb0 + 64;
  const float* bb2 = bb1 + 64;

  float acc[4][8];

  // ---- layer 1: 67 -> 64 ----
  {
    float4 bv = *(const float4*)&bb0[og*4];
    float b4[4] = {bv.x, bv.y, bv.z, bv.w};
#pragma unroll
    for (int oo = 0; oo < 4; ++oo)
#pragma unroll
      for (int cc = 0; cc < 8; ++cc) acc[oo][cc] = b4[oo];
    for (int k = 0; k < 67; ++k) {
      float4 x0 = *(const float4*)&xs[k*XS + cg*8];
      float4 x1 = *(const float4*)&xs[k*XS + cg*8 + 4];
      float4 wv = *(const float4*)&w0[k*64 + og*4];
      float x8[8] = {x0.x,x0.y,x0.z,x0.w,x1.x,x1.y,x1.z,x1.w};
      float w4[4] = {wv.x,wv.y,wv.z,wv.w};
#pragma unroll
      for (int oo = 0; oo < 4; ++oo)
#pragma unroll
        for (int cc = 0; cc < 8; ++cc) acc[oo][cc] = fmaf(w4[oo], x8[cc], acc[oo][cc]);
    }
  }
  __syncthreads();
#pragma unroll
  for (int oo = 0; oo < 4; ++oo) {
    float4 y0, y1;
    y0.x=fmaxf(acc[oo][0],0.f); y0.y=fmaxf(acc[oo][1],0.f);
    y0.z=fmaxf(acc[oo][2],0.f); y0.w=fmaxf(acc[oo][3],0.f);
    y1.x=fmaxf(acc[oo][4],0.f); y1.y=fmaxf(acc[oo][5],0.f);
    y1.z=fmaxf(acc[oo][6],0.f); y1.w=fmaxf(acc[oo][7],0.f);
    *(float4*)&xs[(og*4+oo)*XS + cg*8]     = y0;
    *(float4*)&xs[(og*4+oo)*XS + cg*8 + 4] = y1;
  }
  __syncthreads();

  // ---- layer 2: 64 -> 64 ----
  {
    float4 bv = *(const float4*)&bb1[og*4];
    float b4[4] = {bv.x, bv.y, bv.z, bv.w};
#pragma unroll
    for (int oo = 0; oo < 4; ++oo)
#pragma unroll
      for (int cc = 0; cc < 8; ++cc) acc[oo][cc] = b4[oo];
    for (int k = 0; k < 64; ++k) {
      float4 x0 = *(const float4*)&xs[k*XS + cg*8];
      float4 x1 = *(const float4*)&xs[k*XS + cg*8 + 4];
      float4 wv = *(const float4*)&w1[k*64 + og*4];
      float x8[8] = {x0.x,x0.y,x0.z,x0.w,x1.x,x1.y,x1.z,x1.w};
      float w4[4] = {wv.x,wv.y,wv.z,wv.w};
#pragma unroll
      for (int oo = 0; oo < 4; ++oo)
#pragma unroll
        for (int cc = 0; cc < 8; ++cc) acc[oo][cc] = fmaf(w4[oo], x8[cc], acc[oo][cc]);
    }
  }
  __syncthreads();
#pragma unroll
  for (int oo = 0; oo < 4; ++oo) {
    float4 y0, y1;
    y0.x=fmaxf(acc[oo][0],0.f); y0.y=fmaxf(acc[oo][1],0.f);
    y0.z=fmaxf(acc[oo][2],0.f); y0.w=fmaxf(acc[oo][3],0.f);
    y1.x=fmaxf(acc[oo][4],0.f); y1.y=fmaxf(acc[oo][5],0.f);
    y1.z=fmaxf(acc[oo][6],0.f); y1.w=fmaxf(acc[oo][7],0.f);
    *(float4*)&xs[(og*4+oo)*XS + cg*8]     = y0;
    *(float4*)&xs[(og*4+oo)*XS + cg*8 + 4] = y1;
  }
  __syncthreads();

  // ---- layer 3: 64 -> 128, ReLU + in-register partial maxpool ----
  float acc3[8][8];
  {
    float4 b0v = *(const float4*)&bb2[og*8];
    float4 b1v = *(const float4*)&bb2[og*8 + 4];
    float b8[8] = {b0v.x,b0v.y,b0v.z,b0v.w,b1v.x,b1v.y,b1v.z,b1v.w};
#pragma unroll
    for (int oo = 0; oo < 8; ++oo)
#pragma unroll
      for (int cc = 0; cc < 8; ++cc) acc3[oo][cc] = b8[oo];
    for (int k = 0; k < 64; ++k) {
      float4 x0 = *(const float4*)&xs[k*XS + cg*8];
      float4 x1 = *(const float4*)&xs[k*XS + cg*8 + 4];
      float4 wa = *(const float4*)&w2[k*128 + og*8];
      float4 wb = *(const float4*)&w2[k*128 + og*8 + 4];
      float x8[8] = {x0.x,x0.y,x0.z,x0.w,x1.x,x1.y,x1.z,x1.w};
      float w8[8] = {wa.x,wa.y,wa.z,wa.w,wb.x,wb.y,wb.z,wb.w};
#pragma unroll
      for (int oo = 0; oo < 8; ++oo)
#pragma unroll
        for (int cc = 0; cc < 8; ++cc) acc3[oo][cc] = fmaf(w8[oo], x8[cc], acc3[oo][cc]);
    }
  }
  float pm[8];
#pragma unroll
  for (int oo = 0; oo < 8; ++oo) {
    float v = fmaxf(acc3[oo][0], 0.f);
#pragma unroll
    for (int cc = 1; cc < 8; ++cc) v = fmaxf(v, fmaxf(acc3[oo][cc], 0.f));
    pm[oo] = v;
  }
#pragma unroll
  for (int oo = 0; oo < 8; ++oo) {
    pm[oo] = fmaxf(pm[oo], __shfl_xor(pm[oo], 16));
    pm[oo] = fmaxf(pm[oo], __shfl_xor(pm[oo], 32));
  }
  __syncthreads();
  if ((t & 63) < 16) {
    int w = t >> 6;
#pragma unroll
    for (int oo = 0; oo < 8; ++oo) red[w*128 + og*8 + oo] = pm[oo];
  }
  __syncthreads();

  const int ch = t & 127;
  const float a = att[b*256 + g*128 + ch];
  if (NS == 64) {
    int c = t >> 7;
    float v = fmaxf(red[(2*c)*128 + ch], red[(2*c+1)*128 + ch]);
    int s = (cid0 + c) & 1023;
    outf[((size_t)(b*256 + g*128 + ch)) * 1024 + s] = v * a;
  } else {
#pragma unroll
    for (int kk = 0; kk < 2; ++kk) {
      int c = (t >> 7) * 2 + kk;
      float v = red[c*128 + ch];
      int s = (cid0 + c) & 1023;
      outf[((size_t)(b*256 + g*128 + ch)) * 1024 + s] = v * a;
    }
  }
}

__global__ __launch_bounds__(256, 4) void mlp_kernel(
    const float4* __restrict__ xyzf, const float* __restrict__ feats,
    const float* __restrict__ nxyz, const float* __restrict__ att,
    const int* __restrict__ idx0, const int* __restrict__ idx1,
    const float* __restrict__ wt, float* __restrict__ outf) {
  constexpr int XS = 132;
  __shared__ float xs[67 * XS];
  if (blockIdx.x < 4096)
    mlp_body<32>(blockIdx.x, xs, xyzf, feats, nxyz, att, idx0, wt, outf, 0);
  else
    mlp_body<64>(blockIdx.x - 4096, xs, xyzf, feats, nxyz, att, idx1, wt + WT_G, outf, 1);
}

// ---------------------------------------------------------------------------
extern "C" void kernel_launch(void* const* d_in, const int* in_sizes, int n_in,
                              void* d_out, int out_size, void* d_ws, size_t ws_size,
                              hipStream_t stream) {
  const float* xyz   = (const float*)d_in[0];
  const float* feats = (const float*)d_in[1];
  const float* w_att = (const float*)d_in[2];
  const float* b_att = (const float*)d_in[3];
  const float* w00 = (const float*)d_in[4];
  const float* b00 = (const float*)d_in[5];
  const float* w01 = (const float*)d_in[6];
  const float* b01 = (const float*)d_in[7];
  const float* w02 = (const float*)d_in[8];
  const float* b02 = (const float*)d_in[9];
  const float* w10 = (const float*)d_in[10];
  const float* b10 = (const float*)d_in[11];
  const float* w11 = (const float*)d_in[12];
  const float* b11 = (const float*)d_in[13];
  const float* w12 = (const float*)d_in[14];
  const float* b12 = (const float*)d_in[15];

  float* wsf = (float*)d_ws;
  int*   wsi = (int*)d_ws;
  float4* xyzf = (float4*)(wsf + WS_XYZF);
  float* nxyz  = wsf + WS_NXYZ;
  float* att   = wsf + WS_ATT;
  float* wt    = wsf + WS_WT;
  int* idx0 = wsi + WS_IDX0;
  int* idx1 = wsi + WS_IDX1;

  float* out  = (float*)d_out;
  float* outf = out + B_ * S_ * 3;

  const int wt_blocks = (2*WT_G + 255) / 256;   // 132
  hipLaunchKernelGGL(fps_wt_kernel, dim3(B_ + wt_blocks), dim3(256), 0, stream,
                     xyz, w00, w01, w02, b00, b01, b02, w10, w11, w12, b10, b11, b12,
                     xyzf, wt, nxyz, out);
  hipLaunchKernelGGL(ballq_att_kernel, dim3(B_*S_/4 + B_), dim3(256), 0, stream,
                     xyzf, nxyz, idx0, idx1, w_att, b_att, att);
  hipLaunchKernelGGL(mlp_kernel, dim3(12288), dim3(256), 0, stream,
                     xyzf, feats, nxyz, att, idx0, idx1, wt, outf);
}

// Round 9
// 1717.329 us; speedup vs baseline: 1.4035x; 1.4035x over previous
//
#include <hip/hip_runtime.h>
#include <cstdint>
#include <cstddef>

// ---------------------------------------------------------------------------
// PointNet++ SA module (multi-scale grouping) with attention gate.
// B=16, N=4096, C_IN=64, NPOINT=1024, radii (0.2,0.4), nsamples (32,64),
// MLPs ((64,64,128),(64,64,128)), C_TOTAL=256. Inputs f32, output f32.
// Round 9: revert FPS inner loop to the exact round-7 body (913 us measured).
// Round-8's tree coord-select added ~24 live temps on top of the 64-reg
// px/py/pz/m arrays -> spills in the winner branch -> +1544 cyc/iter on the
// barrier-synchronized critical path (VALUBusy halved, time 1.7x). Keep the
// round-8 launch fusion (fps+wt / ballq+att / mlp32+64), which was neutral.
// ---------------------------------------------------------------------------

constexpr int B_ = 16, N_ = 4096, S_ = 1024;
constexpr int WT_G = 67*64 + 64*64 + 128*64 + 64 + 64 + 128; // 16832 floats/group

// workspace layout in 4-byte units
constexpr int WS_XYZF = 0;                       // float4[B*N]
constexpr int WS_NXYZ = B_*N_*4;                 // float[B*S*3]
constexpr int WS_ATT  = WS_NXYZ + B_*S_*3;       // float[B*256]
constexpr int WS_WT   = WS_ATT + B_*256;         // float[2*WT_G]
constexpr int WS_IDX0 = WS_WT + 2*WT_G;          // int[B*S*32]
constexpr int WS_IDX1 = WS_IDX0 + B_*S_*32;      // int[B*S*64]

// ---------------------------------------------------------------------------
// K1: FPS (blocks 0..15) + weight transpose (blocks 16..147).
// FPS inner loop == round 7 (measured 913 us): no-FMA f32 distance+min
// update (bit-exact vs np), max tree + single reverse ==-scan (smallest p,
// only int temp), DPP uint wave max, ballot+ctz+readlane smallest index,
// winner serial-selects coords (3 float temps — no spill) and forwards
// (val,~idx) key + coords to double-buffered LDS, ONE barrier, all threads
// combine 4 candidates (u64 max tree, lexicographic => np-exact).
// ---------------------------------------------------------------------------
__global__ __launch_bounds__(256) void fps_wt_kernel(
    const float* __restrict__ xyz,
    const float* __restrict__ w00, const float* __restrict__ w01,
    const float* __restrict__ w02, const float* __restrict__ b00,
    const float* __restrict__ b01, const float* __restrict__ b02,
    const float* __restrict__ w10, const float* __restrict__ w11,
    const float* __restrict__ w12, const float* __restrict__ b10,
    const float* __restrict__ b11, const float* __restrict__ b12,
    float4* __restrict__ xyzf, float* __restrict__ wt,
    float* __restrict__ nxyz, float* __restrict__ out_nxyz) {
  constexpr int PPT = 16;
  __shared__ float sx[N_*3];
  __shared__ int   selidx[S_];
  __shared__ alignas(16) unsigned long long redP[2][4];
  __shared__ alignas(16) float4 redC[2][4];

  if (blockIdx.x >= B_) {
    // ---- weight-transpose role (runs on idle CUs during FPS) ----
    int wid = (blockIdx.x - B_) * 256 + threadIdx.x;
    if (wid >= 2*WT_G) return;
    int g = wid / WT_G, r = wid % WT_G;
    float val;
    if (r < 4288) {                    // layer0: w (64,67) -> wt0[c*64+o]
      int c = r >> 6, o = r & 63;
      val = (g ? w10 : w00)[o*67 + c];
    } else if (r < 8384) {             // layer1: w (64,64) -> wt1[c*64+o]
      int rr = r - 4288; int c = rr >> 6, o = rr & 63;
      val = (g ? w11 : w01)[o*64 + c];
    } else if (r < 16576) {            // layer2: w (128,64) -> wt2[c*128+o]
      int rr = r - 8384; int c = rr >> 7, o = rr & 127;
      val = (g ? w12 : w02)[o*64 + c];
    } else {                           // biases
      int rr = r - 16576;
      val = (rr < 64)  ? (g ? b10 : b00)[rr]
          : (rr < 128) ? (g ? b11 : b01)[rr - 64]
                       : (g ? b12 : b02)[rr - 128];
    }
    wt[g*WT_G + r] = val;
    return;
  }

  // ---- FPS role ----
  const int b = blockIdx.x, t = threadIdx.x;
  const int wv = t >> 6;  // wave id 0..3
  const float* xr = xyz + (size_t)b * N_ * 3;
  for (int k = t; k < N_*3; k += 256) sx[k] = xr[k];   // coalesced stage
  if (t == 0) selidx[0] = 0;   // first sampled index is 0 (matches reference)
  __syncthreads();
  float px[PPT], py[PPT], pz[PPT], m[PPT];
#pragma unroll
  for (int p = 0; p < PPT; ++p) {
    int idx = t * PPT + p;
    px[p] = sx[idx*3+0]; py[p] = sx[idx*3+1]; pz[p] = sx[idx*3+2];
    m[p] = 1e10f;
  }
  float lx = sx[0], ly = sx[1], lz = sx[2];
  for (int i = 1; i < S_; ++i) {
    // ---- distance + running-min update (bit-exact np arithmetic) ----
#pragma unroll
    for (int p = 0; p < PPT; ++p) {
      float dx = __fsub_rn(px[p], lx), dy = __fsub_rn(py[p], ly), dz = __fsub_rn(pz[p], lz);
      float d = __fadd_rn(__fadd_rn(__fmul_rn(dx,dx), __fmul_rn(dy,dy)), __fmul_rn(dz,dz));
      m[p] = fminf(m[p], d);
    }
    // ---- local argmax: max tree (v_max3 fusion) + reverse == scan ----
    float h0 = fmaxf(fmaxf(m[0],  m[1]),  fmaxf(m[2],  m[3]));
    float h1 = fmaxf(fmaxf(m[4],  m[5]),  fmaxf(m[6],  m[7]));
    float h2 = fmaxf(fmaxf(m[8],  m[9]),  fmaxf(m[10], m[11]));
    float h3 = fmaxf(fmaxf(m[12], m[13]), fmaxf(m[14], m[15]));
    float bv = fmaxf(fmaxf(h0, h1), fmaxf(h2, h3));
    int bp = PPT - 1;
#pragma unroll
    for (int p = PPT - 2; p >= 0; --p)
      if (m[p] == bv) bp = p;           // ends at smallest p attaining bv
    const int bi = t * PPT + bp;
    // ---- wave max via DPP (uint compare valid: all m >= 0, no NaN) ----
    unsigned vm = __float_as_uint(bv);
#define DPP_MAX(ctrl) { unsigned o = (unsigned)__builtin_amdgcn_update_dpp((int)vm, (int)vm, (ctrl), 0xf, 0xf, false); vm = vm > o ? vm : o; }
    DPP_MAX(0x111)  // row_shr:1
    DPP_MAX(0x112)  // row_shr:2
    DPP_MAX(0x114)  // row_shr:4
    DPP_MAX(0x118)  // row_shr:8
    DPP_MAX(0x142)  // row_bcast:15
    DPP_MAX(0x143)  // row_bcast:31
#undef DPP_MAX
    const unsigned wmaxu = (unsigned)__builtin_amdgcn_readlane((int)vm, 63);
    // smallest index attaining the wave max: lanes are index-ordered
    const unsigned long long mk = __ballot(__float_as_uint(bv) == wmaxu);
    const int fl = (int)__builtin_ctzll(mk);
    const int widx = __builtin_amdgcn_readlane(bi, fl);
    const int par = i & 1;
    // ---- winner lane forwards packed key + its point's coords (serial sel,
    //      3 float temps only — keeps register pressure spill-free) ----
    if (t == (widx >> 4)) {
      const int psel = widx & 15;
      float gx = px[0], gy = py[0], gz = pz[0];
#pragma unroll
      for (int p = 1; p < PPT; ++p)
        if (psel == p) { gx = px[p]; gy = py[p]; gz = pz[p]; }
      redP[par][wv] = ((unsigned long long)wmaxu << 32) | (unsigned)(~widx);
      redC[par][wv] = make_float4(gx, gy, gz, 0.f);
    }
    __syncthreads();
    // ---- all threads: combine 4 wave candidates (broadcast LDS reads) ----
    ulonglong2 pA = *(const ulonglong2*)&redP[par][0];
    ulonglong2 pB = *(const ulonglong2*)&redP[par][2];
    float4 c0 = redC[par][0], c1 = redC[par][1];
    float4 c2 = redC[par][2], c3 = redC[par][3];
    unsigned long long q0 = pA.x > pA.y ? pA.x : pA.y;
    unsigned long long q1 = pB.x > pB.y ? pB.x : pB.y;
    unsigned long long win = q0 > q1 ? q0 : q1;
    const int fi = (int)(~(unsigned)win);   // global index of selected point
    const int ws = fi >> 10;                // winning wave (1024 idx per wave)
    float4 s0 = (ws & 1) ? c1 : c0;
    float4 s1 = (ws & 1) ? c3 : c2;
    float4 fc = (ws & 2) ? s1 : s0;
    lx = fc.x; ly = fc.y; lz = fc.z;
    if (t == 0) selidx[i] = fi;
  }
  __syncthreads();
  // epilogue: coalesced write of new_xyz (ws + out) and xyzf (float4-padded)
  for (int k = t; k < S_; k += 256) {
    int id = selidx[k];
    float x = sx[id*3], y = sx[id*3+1], z = sx[id*3+2];
    int o = (b * S_ + k) * 3;
    nxyz[o] = x; nxyz[o+1] = y; nxyz[o+2] = z;
    out_nxyz[o] = x; out_nxyz[o+1] = y; out_nxyz[o+2] = z;
  }
  for (int k = t; k < N_; k += 256) {
    float4 v; v.x = sx[k*3]; v.y = sx[k*3+1]; v.z = sx[k*3+2]; v.w = 0.f;
    xyzf[b * N_ + k] = v;
  }
}

// ---------------------------------------------------------------------------
// K2: fused dual-radius ball query (blocks 0..4095) + attention gate
// (blocks 4096..4111). Ball query: bit-exact d2 < r2 in non-contracted f32;
// first-NS in ascending index order; pad with first hit.
// ---------------------------------------------------------------------------
__global__ __launch_bounds__(256) void ballq_att_kernel(
    const float4* __restrict__ xyzf, const float* __restrict__ nxyz,
    int* __restrict__ idx0buf, int* __restrict__ idx1buf,
    const float* __restrict__ w_att, const float* __restrict__ b_att,
    float* __restrict__ att) {
  __shared__ float ai[3 * S_];
  if (blockIdx.x >= B_*S_/4) {
    // ---- attention role ----
    int b = blockIdx.x - B_*S_/4, t = threadIdx.x;
    for (int k = t; k < 3 * S_; k += 256) {
      int d = k >> 10, s = k & 1023;
      ai[k] = nxyz[(b * S_ + s) * 3 + d];
    }
    __syncthreads();
    float acc = b_att[t];
#pragma unroll 8
    for (int k = 0; k < 3 * S_; ++k)
      acc = fmaf(ai[k], w_att[k * 256 + t], acc);
    att[b * 256 + t] = 1.f / (1.f + expf(-acc));
    return;
  }
  // ---- ball-query role ----
  const float r2a = (float)(0.2 * 0.2), r2b = (float)(0.4 * 0.4);
  int lane = threadIdx.x & 63;
  int cid = blockIdx.x * 4 + (threadIdx.x >> 6);
  int b = cid >> 10;
  float cx = nxyz[cid*3], cy = nxyz[cid*3+1], cz = nxyz[cid*3+2];
  const float4* xb = xyzf + b * N_;
  int cnt0 = 0, cnt1 = 0, first0 = 0, first1 = 0;
  const unsigned long long below = (1ull << lane) - 1ull;
  for (int base = 0; base < N_; base += 64) {
    float4 P = xb[base + lane];
    float dx = __fsub_rn(cx, P.x), dy = __fsub_rn(cy, P.y), dz = __fsub_rn(cz, P.z);
    float d2 = __fadd_rn(__fadd_rn(__fmul_rn(dx,dx), __fmul_rn(dy,dy)), __fmul_rn(dz,dz));
    bool h0 = d2 < r2a, h1 = d2 < r2b;
    unsigned long long m0 = __ballot(h0), m1 = __ballot(h1);
    if (cnt0 == 0 && m0 != 0ull) first0 = base + (int)__builtin_ctzll(m0);
    if (cnt1 == 0 && m1 != 0ull) first1 = base + (int)__builtin_ctzll(m1);
    if (h0) {
      int pos = cnt0 + (int)__popcll(m0 & below);
      if (pos < 32) idx0buf[cid * 32 + pos] = base + lane;
    }
    if (h1) {
      int pos = cnt1 + (int)__popcll(m1 & below);
      if (pos < 64) idx1buf[cid * 64 + pos] = base + lane;
    }
    cnt0 += (int)__popcll(m0);
    cnt1 += (int)__popcll(m1);
    if (cnt0 >= 32 && cnt1 >= 64) break;
  }
  if (cnt0 < 32)
    for (int p = cnt0 + lane; p < 32; p += 64) idx0buf[cid * 32 + p] = first0;
  if (cnt1 < 64)
    for (int p = cnt1 + lane; p < 64; p += 64) idx1buf[cid * 64 + p] = first1;
}

// ---------------------------------------------------------------------------
// K3: GEMM-tiled fused group + MLP + maxpool + attention + store.
// 256 threads (4 waves), 128 columns/block. og = t&15, cg = t>>4.
// Both groups dispatched from one kernel (uniform per-block branch).
// ---------------------------------------------------------------------------
template<int NS>
__device__ __forceinline__ void mlp_body(int bi, float* xs,
    const float4* __restrict__ xyzf, const float* __restrict__ feats,
    const float* __restrict__ nxyz, const float* __restrict__ att,
    const int* __restrict__ idxbuf, const float* __restrict__ wt,
    float* __restrict__ outf, int g) {
  constexpr int NCEN = 128 / NS;
  constexpr int XS = 132;
  float* red = xs;
  const int t = threadIdx.x;
  const int cid0 = bi * NCEN;
  const int b = cid0 >> 10;

  {
    const int col = t & 127, h = t >> 7;
    const int cidg = cid0 + col / NS;
    const int j = col % NS;
    const int p = idxbuf[cidg * NS + j];
    if (h == 0) {
      float4 P = xyzf[b * N_ + p];
      xs[0*XS+col] = __fsub_rn(P.x, nxyz[cidg*3+0]);
      xs[1*XS+col] = __fsub_rn(P.y, nxyz[cidg*3+1]);
      xs[2*XS+col] = __fsub_rn(P.z, nxyz[cidg*3+2]);
    }
    const float4* f4 = (const float4*)(feats + (size_t)(b*N_+p)*64) + h*8;
#pragma unroll
    for (int q = 0; q < 8; ++q) {
      float4 u = f4[q];
      int r = 3 + h*32 + q*4;
      xs[(r+0)*XS+col]=u.x; xs[(r+1)*XS+col]=u.y; xs[(r+2)*XS+col]=u.z; xs[(r+3)*XS+col]=u.w;
    }
  }
  __syncthreads();

  const int og = t & 15, cg = t >> 4;
  const float* w0  = wt;
  const float* w1  = wt + 67*64;
  const float* w2  = w1 + 64*64;
  const float* bb0 = w2 + 64*128;
  const float* bb1 = bb0 + 64;
  const float* bb2 = bb1 + 64;

  float acc[4][8];

  // ---- layer 1: 67 -> 64 ----
  {
    float4 bv = *(const float4*)&bb0[og*4];
    float b4[4] = {bv.x, bv.y, bv.z, bv.w};
#pragma unroll
    for (int oo = 0; oo < 4; ++oo)
#pragma unroll
      for (int cc = 0; cc < 8; ++cc) acc[oo][cc] = b4[oo];
    for (int k = 0; k < 67; ++k) {
      float4 x0 = *(const float4*)&xs[k*XS + cg*8];
      float4 x1 = *(const float4*)&xs[k*XS + cg*8 + 4];
      float4 wv = *(const float4*)&w0[k*64 + og*4];
      float x8[8] = {x0.x,x0.y,x0.z,x0.w,x1.x,x1.y,x1.z,x1.w};
      float w4[4] = {wv.x,wv.y,wv.z,wv.w};
#pragma unroll
      for (int oo = 0; oo < 4; ++oo)
#pragma unroll
        for (int cc = 0; cc < 8; ++cc) acc[oo][cc] = fmaf(w4[oo], x8[cc], acc[oo][cc]);
    }
  }
  __syncthreads();
#pragma unroll
  for (int oo = 0; oo < 4; ++oo) {
    float4 y0, y1;
    y0.x=fmaxf(acc[oo][0],0.f); y0.y=fmaxf(acc[oo][1],0.f);
    y0.z=fmaxf(acc[oo][2],0.f); y0.w=fmaxf(acc[oo][3],0.f);
    y1.x=fmaxf(acc[oo][4],0.f); y1.y=fmaxf(acc[oo][5],0.f);
    y1.z=fmaxf(acc[oo][6],0.f); y1.w=fmaxf(acc[oo][7],0.f);
    *(float4*)&xs[(og*4+oo)*XS + cg*8]     = y0;
    *(float4*)&xs[(og*4+oo)*XS + cg*8 + 4] = y1;
  }
  __syncthreads();

  // ---- layer 2: 64 -> 64 ----
  {
    float4 bv = *(const float4*)&bb1[og*4];
    float b4[4] = {bv.x, bv.y, bv.z, bv.w};
#pragma unroll
    for (int oo = 0; oo < 4; ++oo)
#pragma unroll
      for (int cc = 0; cc < 8; ++cc) acc[oo][cc] = b4[oo];
    for (int k = 0; k < 64; ++k) {
      float4 x0 = *(const float4*)&xs[k*XS + cg*8];
      float4 x1 = *(const float4*)&xs[k*XS + cg*8 + 4];
      float4 wv = *(const float4*)&w1[k*64 + og*4];
      float x8[8] = {x0.x,x0.y,x0.z,x0.w,x1.x,x1.y,x1.z,x1.w};
      float w4[4] = {wv.x,wv.y,wv.z,wv.w};
#pragma unroll
      for (int oo = 0; oo < 4; ++oo)
#pragma unroll
        for (int cc = 0; cc < 8; ++cc) acc[oo][cc] = fmaf(w4[oo], x8[cc], acc[oo][cc]);
    }
  }
  __syncthreads();
#pragma unroll
  for (int oo = 0; oo < 4; ++oo) {
    float4 y0, y1;
    y0.x=fmaxf(acc[oo][0],0.f); y0.y=fmaxf(acc[oo][1],0.f);
    y0.z=fmaxf(acc[oo][2],0.f); y0.w=fmaxf(acc[oo][3],0.f);
    y1.x=fmaxf(acc[oo][4],0.f); y1.y=fmaxf(acc[oo][5],0.f);
    y1.z=fmaxf(acc[oo][6],0.f); y1.w=fmaxf(acc[oo][7],0.f);
    *(float4*)&xs[(og*4+oo)*XS + cg*8]     = y0;
    *(float4*)&xs[(og*4+oo)*XS + cg*8 + 4] = y1;
  }
  __syncthreads();

  // ---- layer 3: 64 -> 128, ReLU + in-register partial maxpool ----
  float acc3[8][8];
  {
    float4 b0v = *(const float4*)&bb2[og*8];
    float4 b1v = *(const float4*)&bb2[og*8 + 4];
    float b8[8] = {b0v.x,b0v.y,b0v.z,b0v.w,b1v.x,b1v.y,b1v.z,b1v.w};
#pragma unroll
    for (int oo = 0; oo < 8; ++oo)
#pragma unroll
      for (int cc = 0; cc < 8; ++cc) acc3[oo][cc] = b8[oo];
    for (int k = 0; k < 64; ++k) {
      float4 x0 = *(const float4*)&xs[k*XS + cg*8];
      float4 x1 = *(const float4*)&xs[k*XS + cg*8 + 4];
      float4 wa = *(const float4*)&w2[k*128 + og*8];
      float4 wb = *(const float4*)&w2[k*128 + og*8 + 4];
      float x8[8] = {x0.x,x0.y,x0.z,x0.w,x1.x,x1.y,x1.z,x1.w};
      float w8[8] = {wa.x,wa.y,wa.z,wa.w,wb.x,wb.y,wb.z,wb.w};
#pragma unroll
      for (int oo = 0; oo < 8; ++oo)
#pragma unroll
        for (int cc = 0; cc < 8; ++cc) acc3[oo][cc] = fmaf(w8[oo], x8[cc], acc3[oo][cc]);
    }
  }
  float pm[8];
#pragma unroll
  for (int oo = 0; oo < 8; ++oo) {
    float v = fmaxf(acc3[oo][0], 0.f);
#pragma unroll
    for (int cc = 1; cc < 8; ++cc) v = fmaxf(v, fmaxf(acc3[oo][cc], 0.f));
    pm[oo] = v;
  }
#pragma unroll
  for (int oo = 0; oo < 8; ++oo) {
    pm[oo] = fmaxf(pm[oo], __shfl_xor(pm[oo], 16));
    pm[oo] = fmaxf(pm[oo], __shfl_xor(pm[oo], 32));
  }
  __syncthreads();
  if ((t & 63) < 16) {
    int w = t >> 6;
#pragma unroll
    for (int oo = 0; oo < 8; ++oo) red[w*128 + og*8 + oo] = pm[oo];
  }
  __syncthreads();

  const int ch = t & 127;
  const float a = att[b*256 + g*128 + ch];
  if (NS == 64) {
    int c = t >> 7;
    float v = fmaxf(red[(2*c)*128 + ch], red[(2*c+1)*128 + ch]);
    int s = (cid0 + c) & 1023;
    outf[((size_t)(b*256 + g*128 + ch)) * 1024 + s] = v * a;
  } else {
#pragma unroll
    for (int kk = 0; kk < 2; ++kk) {
      int c = (t >> 7) * 2 + kk;
      float v = red[c*128 + ch];
      int s = (cid0 + c) & 1023;
      outf[((size_t)(b*256 + g*128 + ch)) * 1024 + s] = v * a;
    }
  }
}

__global__ __launch_bounds__(256, 4) void mlp_kernel(
    const float4* __restrict__ xyzf, const float* __restrict__ feats,
    const float* __restrict__ nxyz, const float* __restrict__ att,
    const int* __restrict__ idx0, const int* __restrict__ idx1,
    const float* __restrict__ wt, float* __restrict__ outf) {
  constexpr int XS = 132;
  __shared__ float xs[67 * XS];
  if (blockIdx.x < 4096)
    mlp_body<32>(blockIdx.x, xs, xyzf, feats, nxyz, att, idx0, wt, outf, 0);
  else
    mlp_body<64>(blockIdx.x - 4096, xs, xyzf, feats, nxyz, att, idx1, wt + WT_G, outf, 1);
}

// ---------------------------------------------------------------------------
extern "C" void kernel_launch(void* const* d_in, const int* in_sizes, int n_in,
                              void* d_out, int out_size, void* d_ws, size_t ws_size,
                              hipStream_t stream) {
  const float* xyz   = (const float*)d_in[0];
  const float* feats = (const float*)d_in[1];
  const float* w_att = (const float*)d_in[2];
  const float* b_att = (const float*)d_in[3];
  const float* w00 = (const float*)d_in[4];
  const float* b00 = (const float*)d_in[5];
  const float* w01 = (const float*)d_in[6];
  const float* b01 = (const float*)d_in[7];
  const float* w02 = (const float*)d_in[8];
  const float* b02 = (const float*)d_in[9];
  const float* w10 = (const float*)d_in[10];
  const float* b10 = (const float*)d_in[11];
  const float* w11 = (const float*)d_in[12];
  const float* b11 = (const float*)d_in[13];
  const float* w12 = (const float*)d_in[14];
  const float* b12 = (const float*)d_in[15];

  float* wsf = (float*)d_ws;
  int*   wsi = (int*)d_ws;
  float4* xyzf = (float4*)(wsf + WS_XYZF);
  float* nxyz  = wsf + WS_NXYZ;
  float* att   = wsf + WS_ATT;
  float* wt    = wsf + WS_WT;
  int* idx0 = wsi + WS_IDX0;
  int* idx1 = wsi + WS_IDX1;

  float* out  = (float*)d_out;
  float* outf = out + B_ * S_ * 3;

  const int wt_blocks = (2*WT_G + 255) / 256;   // 132
  hipLaunchKernelGGL(fps_wt_kernel, dim3(B_ + wt_blocks), dim3(256), 0, stream,
                     xyz, w00, w01, w02, b00, b01, b02, w10, w11, w12, b10, b11, b12,
                     xyzf, wt, nxyz, out);
  hipLaunchKernelGGL(ballq_att_kernel, dim3(B_*S_/4 + B_), dim3(256), 0, stream,
                     xyzf, nxyz, idx0, idx1, w_att, b_att, att);
  hipLaunchKernelGGL(mlp_kernel, dim3(12288), dim3(256), 0, stream,
                     xyzf, feats, nxyz, att, idx0, idx1, wt, outf);
}